// Round 1
// baseline (497.284 us; speedup 1.0000x reference)
//
#include <hip/hip_runtime.h>
#include <math.h>

#define NB 8
#define NA 720
#define ND 1024
#define NH 512
#define NW 512

// DS = 4/1024 = 2^-8 exactly; 1/DS = 256. S0 = -2 + DS/2 -> -S0/DS = 511.5
// DX = 2/512 = 2^-8... actually 0.00390625. IMG_MIN = -1.
#define DXF 0.00390625f
#define IMG_MIN_F (-1.0f)
#define DTH_D (3.14159265358979323846 / 720.0)

// ---------------- Kernel 1: 11-tap conv along detector, left pad 10, *DTH ---------------
__global__ __launch_bounds__(256) void conv_kernel(const float* __restrict__ x,
                                                   const float* __restrict__ w,
                                                   float* __restrict__ y) {
    int row = blockIdx.x;                 // b*720 + a
    const float* xr = x + (size_t)row * ND;
    float* yr = y + (size_t)row * ND;

    __shared__ float s[16 + ND];
    __shared__ float wk[16];

    int tid = threadIdx.x;                // 256 threads
    if (tid < 16) s[tid] = 0.0f;          // zero pad region (need 10, do 16)
    if (tid < 11) wk[tid] = w[tid] * (float)DTH_D;

    // load row as float4: 256 * 4 = 1024
    float4 v = ((const float4*)xr)[tid];
    *(float4*)&s[16 + tid * 4] = v;
    __syncthreads();

    int d0 = tid * 4;
    float o0 = 0.f, o1 = 0.f, o2 = 0.f, o3 = 0.f;
    // y[d] = sum_{k=0}^{10} x[d + k - 10] * w[k] ; x index -> s[16 + d + k - 10]
#pragma unroll
    for (int k = 0; k < 11; ++k) {
        float wv = wk[k];
        o0 = fmaf(wv, s[6 + d0 + k], o0);
        o1 = fmaf(wv, s[7 + d0 + k], o1);
        o2 = fmaf(wv, s[8 + d0 + k], o2);
        o3 = fmaf(wv, s[9 + d0 + k], o3);
    }
    *(float4*)&yr[d0] = make_float4(o0, o1, o2, o3);
}

// ---------------- Kernel 2: per-angle tables: 256*cos(th), 256*sin(th) ---------------
__global__ void table_kernel(float* __restrict__ ct, float* __restrict__ st) {
    int a = blockIdx.x * blockDim.x + threadIdx.x;
    if (a < NA) {
        // THETAS computed in f64 then cast to f32 in the reference
        float th = (float)((a + 0.5) * DTH_D);
        double thd = (double)th;
        ct[a] = (float)(cos(thd) * 256.0);
        st[a] = (float)(sin(thd) * 256.0);
    }
}

// ---------------- Kernel 3: backprojection ---------------
// grid: 8 batches * (4 i-tiles * 8 j-tiles) = 256 blocks, 512 threads.
// Tile = 128 rows (i) x 64 cols (j). lane = j (stride-1 LDS), wave id = i row offset.
// Each thread: 16 i's (stride 8), 1 j. Double-buffered LDS, 8 angle rows per chunk.

__device__ __forceinline__ void async_ld16(const float* g, float* l) {
    __builtin_amdgcn_global_load_lds((const __attribute__((address_space(1))) void*)g,
                                     (__attribute__((address_space(3))) void*)l,
                                     16, 0, 0);
}

#define WAIT_VM0_BARRIER() do { \
    asm volatile("" ::: "memory"); \
    __builtin_amdgcn_s_waitcnt(0x0F70); /* vmcnt(0), expcnt/lgkmcnt untouched */ \
    __builtin_amdgcn_s_barrier(); \
    asm volatile("" ::: "memory"); \
} while (0)

__global__ __launch_bounds__(512) void bp_kernel(const float* __restrict__ sino,
                                                 const float* __restrict__ ct,
                                                 const float* __restrict__ st,
                                                 float* __restrict__ out) {
    int bid = blockIdx.x;
    int b = bid >> 5;            // 0..7
    int tile = bid & 31;
    int ibase = (tile >> 3) * 128;
    int jbase = (tile & 7) * 64;

    int tid = threadIdx.x;
    int lane = tid & 63;
    int wv = tid >> 6;           // 0..7

    int j = jbase + lane;
    float pxj = IMG_MIN_F + (j + 0.5f) * DXF;
    int i0 = ibase + wv;         // i_r = i0 + 8*r
    float pxi0 = IMG_MIN_F + (i0 + 0.5f) * DXF;

    __shared__ float buf[2][8 * ND];   // 64 KB

    const float* srow = sino + (size_t)b * (NA * ND);

    float acc[16];
#pragma unroll
    for (int r = 0; r < 16; ++r) acc[r] = 0.0f;

    // stage chunk c into buffer bsel: wave wv stages angle row (c*8 + wv)
    // 1024 floats = 4 parts x (64 lanes x 16B)
    {
        const float* rp = srow + (size_t)(0 * 8 + wv) * ND + lane * 4;
        float* lp = &buf[0][wv * ND];
#pragma unroll
        for (int p = 0; p < 4; ++p) async_ld16(rp + p * 256, lp + p * 256);
    }
    WAIT_VM0_BARRIER();

    const float c0u = 511.5f;    // -S0/DS

    for (int c = 0; c < 90; ++c) {
        int cur = c & 1;
        if (c + 1 < 90) {
            const float* rp = srow + (size_t)((c + 1) * 8 + wv) * ND + lane * 4;
            float* lp = &buf[cur ^ 1][wv * ND];
#pragma unroll
            for (int p = 0; p < 4; ++p) async_ld16(rp + p * 256, lp + p * 256);
        }
        const float* lbuf = buf[cur];
#pragma unroll
        for (int k = 0; k < 8; ++k) {
            int a = c * 8 + k;
            float ca = ct[a];                    // uniform -> s_load
            float sa = st[a];
            float u = fmaf(pxj, sa, fmaf(pxi0, ca, c0u));
            float du = ca * (8.0f * DXF);
            const float* row = lbuf + k * ND;
#pragma unroll
            for (int r = 0; r < 16; ++r) {
                int iu = (int)u;                 // u in [149, 874): trunc == floor
                float f = u - (float)iu;
                float v0 = row[iu];
                float v1 = row[iu + 1];
                acc[r] += v0 + f * (v1 - v0);
                u += du;
            }
        }
        WAIT_VM0_BARRIER();
    }

    float* orow = out + (size_t)b * (NH * NW);
#pragma unroll
    for (int r = 0; r < 16; ++r) {
        int i = i0 + 8 * r;
        orow[i * NW + j] = acc[r];
    }
}

extern "C" void kernel_launch(void* const* d_in, const int* in_sizes, int n_in,
                              void* d_out, int out_size, void* d_ws, size_t ws_size,
                              hipStream_t stream) {
    const float* x = (const float*)d_in[0];      // [8,1,720,1024] f32
    const float* w = (const float*)d_in[1];      // [1,1,1,11] f32
    float* out = (float*)d_out;                  // [8,1,512,512] f32
    float* ws = (float*)d_ws;

    float* sino = ws;                            // 8*720*1024 floats = 23.6 MB
    float* ct = ws + (size_t)NB * NA * ND;       // 720 floats
    float* st = ct + NA;                         // 720 floats

    conv_kernel<<<dim3(NB * NA), dim3(256), 0, stream>>>(x, w, sino);
    table_kernel<<<dim3(3), dim3(256), 0, stream>>>(ct, st);
    bp_kernel<<<dim3(256), dim3(512), 0, stream>>>(sino, ct, st, out);
}